// Round 13
// baseline (387.430 us; speedup 1.0000x reference)
//
#include <hip/hip_runtime.h>

#define NNODES 50000
#define NEDGES 800000
#define NGRAPH 512
#define DCAP 48   // padded edge slots per node; Poisson(16): P(deg>=48) ~1e-12

typedef short bf16x8 __attribute__((ext_vector_type(8)));
typedef unsigned short u16x8 __attribute__((ext_vector_type(8)));
typedef float f32x4 __attribute__((ext_vector_type(4)));
typedef unsigned long long u64;

// ---------- bf16 <-> fp32 helpers ----------
static __device__ __forceinline__ float b2f(unsigned short u) {
    return __uint_as_float(((unsigned)u) << 16);
}
static __device__ __forceinline__ unsigned short f2b(float f) {
    unsigned u = __float_as_uint(f);
    unsigned r = (u + 0x7fffu + ((u >> 16) & 1u)) >> 16;  // round-nearest-even
    return (unsigned short)r;
}

// row-fragment loads (bf16 rows)
static __device__ __forceinline__ void ldrow(const unsigned short* X, size_t off, float (&v)[2]) {
    unsigned u = *(const unsigned*)(X + off);
    v[0] = b2f((unsigned short)(u & 0xffff));
    v[1] = b2f((unsigned short)(u >> 16));
}
static __device__ __forceinline__ void ldrow(const unsigned short* X, size_t off, float (&v)[4]) {
    uint2 u = *(const uint2*)(X + off);
    v[0] = b2f((unsigned short)(u.x & 0xffff));
    v[1] = b2f((unsigned short)(u.x >> 16));
    v[2] = b2f((unsigned short)(u.y & 0xffff));
    v[3] = b2f((unsigned short)(u.y >> 16));
}

// ---------- setup: deg_cnt init + gp zero ----------
__global__ void k_setup(u64* deg_cnt, int* gp) {
    int i = blockIdx.x * 256 + threadIdx.x;
    if (i < NNODES) deg_cnt[i] = (u64)(1u << 24);   // self-loop w=1 (8.24 fixed)
    if (i < NGRAPH * 512) gp[i] = 0;                // +0.0f bits; relu pool >= 0
}

// count + DIRECT padded-CSR placement: u64 atomic returns old count = slot.
__global__ __launch_bounds__(256) void k_count(const int4* __restrict__ ei_s,
                                               const int4* __restrict__ ei_d,
                                               const float4* __restrict__ ew4,
                                               u64* deg_cnt,
                                               unsigned* __restrict__ edges) {
    int t = blockIdx.x * 256 + threadIdx.x;
    if (t >= NEDGES / 4) return;
    int4 ss = ei_s[t];
    int4 dd = ei_d[t];
    float4 ww = ew4[t];
    int s[4] = {ss.x, ss.y, ss.z, ss.w};
    int d[4] = {dd.x, dd.y, dd.z, dd.w};
    float w[4] = {ww.x, ww.y, ww.z, ww.w};
    int slot[4];
    #pragma unroll
    for (int u = 0; u < 4; ++u) {
        unsigned fixed = __float2uint_rn(w[u] * 16777216.0f);  // 2^24; ew in [0,1)
        u64 old = atomicAdd(&deg_cnt[d[u]], ((u64)1 << 32) | fixed);
        slot[u] = (int)(old >> 32);
        if (slot[u] > DCAP - 1) slot[u] = DCAP - 1;  // never fires (safety)
    }
    #pragma unroll
    for (int u = 0; u < 4; ++u)
        edges[(unsigned)d[u] * DCAP + slot[u]] = ((unsigned)f2b(w[u]) << 16) | (unsigned)s[u];
}

// dinv from packed degree
__global__ void k_prep(const u64* __restrict__ deg_cnt, float* __restrict__ dinv) {
    int i = blockIdx.x * 256 + threadIdx.x;
    if (i < NNODES)
        dinv[i] = rsqrtf((float)(unsigned)(deg_cnt[i] & 0xffffffffull) * 5.9604645e-8f);  // *2^-24
}

// ---------- all 5 weight transposes: W[K][N] fp32 -> WT[N][K] bf16 ----------
__global__ void k_wt_all(const float* __restrict__ W1, const float* __restrict__ W2,
                         const float* __restrict__ W3, const float* __restrict__ Wf1,
                         const float* __restrict__ Wf2,
                         unsigned short* __restrict__ T1, unsigned short* __restrict__ T2,
                         unsigned short* __restrict__ T3, unsigned short* __restrict__ Tf1,
                         unsigned short* __restrict__ Tf2) {
    int i = blockIdx.x * 256 + threadIdx.x;
    const float* W; unsigned short* T; int K, ns;
    if (i < 16384)        { W = W1;  T = T1;  K = 128;  ns = 7;  }
    else if (i < 49152)   { W = W2;  T = T2;  K = 128;  ns = 8;  i -= 16384; }
    else if (i < 180224)  { W = W3;  T = T3;  K = 256;  ns = 9;  i -= 49152; }
    else if (i < 704512)  { W = Wf1; T = Tf1; K = 512;  ns = 10; i -= 180224; }
    else if (i < 835584)  { W = Wf2; T = Tf2; K = 1024; ns = 7;  i -= 704512; }
    else return;
    int k = i >> ns, n = i & ((1 << ns) - 1);
    T[(size_t)n * K + k] = f2b(W[i]);
}

// fp32 -> bf16 with per-row dinv scale: x'[i,:] = dinv[i]*x[i,:]  (F=128)
__global__ void k_cvt4(const float* __restrict__ X, const float* __restrict__ dinv,
                       unsigned short* __restrict__ Y, int n4) {
    int i = blockIdx.x * 256 + threadIdx.x;
    if (i < n4) {
        float4 v = ((const float4*)X)[i];
        float d = dinv[i >> 5];   // 32 float4 per 128-wide row
        uint2 o;
        o.x = (unsigned)f2b(v.x * d) | ((unsigned)f2b(v.y * d) << 16);
        o.y = (unsigned)f2b(v.z * d) | ((unsigned)f2b(v.w * d) << 16);
        ((uint2*)Y)[i] = o;
    }
}

// ---------- aggregation: Z[d,:] = dinv[d] * (X'[d,:] + sum_e ew_e * X'[src_e,:]) ----------
template <int VEC>
__global__ __launch_bounds__(256) void k_aggregate(const unsigned short* __restrict__ X,
                                                   const u64* __restrict__ deg_cnt,
                                                   const unsigned* __restrict__ edges,
                                                   const float* __restrict__ dinv,
                                                   unsigned short* __restrict__ Z) {
    const int F = 64 * VEC;
    const int wave = threadIdx.x >> 6, lane = threadIdx.x & 63;
    const int node = blockIdx.x * 4 + wave;
    if (node >= NNODES) return;
    const int fo = lane * VEC;
    const float di = dinv[node];
    const int cnt = (int)(deg_cnt[node] >> 32);
    const unsigned* erow = edges + (unsigned)node * DCAP;

    float acc[VEC], v[VEC];
    ldrow(X, (size_t)node * F + fo, v);
    #pragma unroll
    for (int j = 0; j < VEC; ++j) acc[j] = v[j];

    int e = 0;
    for (; e + 8 <= cnt; e += 8) {
        unsigned pk[8];
        float vv[8][VEC];
        #pragma unroll
        for (int u = 0; u < 8; ++u) pk[u] = erow[e + u];
        #pragma unroll
        for (int u = 0; u < 8; ++u) ldrow(X, (size_t)(pk[u] & 0xffffu) * F + fo, vv[u]);
        #pragma unroll
        for (int u = 0; u < 8; ++u) {
            float c = b2f((unsigned short)(pk[u] >> 16));
            #pragma unroll
            for (int j = 0; j < VEC; ++j) acc[j] += c * vv[u][j];
        }
    }
    for (; e + 4 <= cnt; e += 4) {
        unsigned pk[4];
        float vv[4][VEC];
        #pragma unroll
        for (int u = 0; u < 4; ++u) pk[u] = erow[e + u];
        #pragma unroll
        for (int u = 0; u < 4; ++u) ldrow(X, (size_t)(pk[u] & 0xffffu) * F + fo, vv[u]);
        #pragma unroll
        for (int u = 0; u < 4; ++u) {
            float c = b2f((unsigned short)(pk[u] >> 16));
            #pragma unroll
            for (int j = 0; j < VEC; ++j) acc[j] += c * vv[u][j];
        }
    }
    for (; e < cnt; ++e) {
        unsigned pe = erow[e];
        float c = b2f((unsigned short)(pe >> 16));
        ldrow(X, (size_t)(pe & 0xffffu) * F + fo, v);
        #pragma unroll
        for (int j = 0; j < VEC; ++j) acc[j] += c * v[j];
    }

    if constexpr (VEC == 2) {
        unsigned o = (unsigned)f2b(di * acc[0]) | ((unsigned)f2b(di * acc[1]) << 16);
        *(unsigned*)(Z + (size_t)node * F + fo) = o;
    } else {
        uint2 o;
        o.x = (unsigned)f2b(di * acc[0]) | ((unsigned)f2b(di * acc[1]) << 16);
        o.y = (unsigned)f2b(di * acc[2]) | ((unsigned)f2b(di * acc[3]) << 16);
        *(uint2*)(Z + (size_t)node * F + fo) = o;
    }
}

// ---------- conv GEMM with full-K A-tile resident in LDS, n-chunk loop inside ----------
// KK in {128,256}. Block = 64 rows; A staged ONCE (A-traffic x1 regardless of N).
// Per n-chunk (128 cols): BK=32 Bs staging + MFMA; epilogue per chunk.
// CMODE 0: bf16 store + relu (optional rscale). 2: fused per-graph relu+max-pool into gp.
template <int CMODE, int KK>
__global__ __launch_bounds__(256) void k_gemm_conv(const unsigned short* __restrict__ A,
                                                   const unsigned short* __restrict__ WT,
                                                   const float* __restrict__ bias,
                                                   unsigned short* __restrict__ C,
                                                   const int* __restrict__ batch,
                                                   int* __restrict__ gp,
                                                   const float* __restrict__ rscale,
                                                   int M, int N) {
    constexpr int LDA = KK + 8;   // padded row stride (shorts)
    __shared__ unsigned short As[64 * LDA];
    __shared__ unsigned short Bs[128 * 40];
    __shared__ float pools[2][2][128];
    const int tid = threadIdx.x;
    const int m0 = blockIdx.x * 64;
    const int wave = tid >> 6, lane = tid & 63;
    const int wm = (wave >> 1) * 32;
    const int wn = (wave & 1) * 64;
    const int quad = lane >> 4, mrow = lane & 15;

    // stage full A tile (64 x KK)
    #pragma unroll
    for (int j = 0; j < KK / 32; ++j) {
        int idx = j * 256 + tid;
        int row = idx / (KK / 8);
        int ko = (idx % (KK / 8)) * 8;
        u16x8 av = {};
        if (m0 + row < M) av = *(const u16x8*)(A + (size_t)(m0 + row) * KK + ko);
        *(u16x8*)&As[row * LDA + ko] = av;
    }
    __syncthreads();

    // pool bookkeeping (CMODE 2)
    int g0 = 0, gl = 0;
    int gid[8]; bool rok[8];
    if constexpr (CMODE == 2) {
        g0 = batch[m0];
        int last = m0 + 63; if (last >= M) last = M - 1;
        gl = batch[last];
        #pragma unroll
        for (int mt = 0; mt < 2; ++mt)
            #pragma unroll
            for (int r = 0; r < 4; ++r) {
                int row = m0 + wm + mt * 16 + quad * 4 + r;
                rok[mt * 4 + r] = row < M;
                gid[mt * 4 + r] = (row < M) ? batch[row] : -1;
            }
    }

    for (int n0 = 0; n0 < N; n0 += 128) {
        f32x4 acc[2][4] = {};
        for (int k0 = 0; k0 < KK; k0 += 32) {
            #pragma unroll
            for (int j = 0; j < 2; ++j) {
                int idx = j * 256 + tid;
                int row = idx >> 2;
                int ko = (idx & 3) * 8;
                *(u16x8*)&Bs[row * 40 + ko] = *(const u16x8*)(WT + (size_t)(n0 + row) * KK + k0 + ko);
            }
            __syncthreads();
            bf16x8 af[2], bf[4];
            #pragma unroll
            for (int mt = 0; mt < 2; ++mt)
                af[mt] = *(const bf16x8*)&As[(wm + mt * 16 + mrow) * LDA + k0 + quad * 8];
            #pragma unroll
            for (int nt = 0; nt < 4; ++nt)
                bf[nt] = *(const bf16x8*)&Bs[(wn + nt * 16 + mrow) * 40 + quad * 8];
            #pragma unroll
            for (int mt = 0; mt < 2; ++mt)
                #pragma unroll
                for (int nt = 0; nt < 4; ++nt)
                    acc[mt][nt] = __builtin_amdgcn_mfma_f32_16x16x32_bf16(af[mt], bf[nt], acc[mt][nt], 0, 0, 0);
            __syncthreads();
        }

        float bn[4];
        #pragma unroll
        for (int nt = 0; nt < 4; ++nt) bn[nt] = bias[n0 + wn + nt * 16 + mrow];

        if constexpr (CMODE == 0) {
            #pragma unroll
            for (int mt = 0; mt < 2; ++mt) {
                #pragma unroll
                for (int r = 0; r < 4; ++r) {
                    int row = m0 + wm + mt * 16 + quad * 4 + r;
                    if (row < M) {
                        float rs = rscale ? rscale[row] : 1.0f;
                        #pragma unroll
                        for (int nt = 0; nt < 4; ++nt) {
                            float v = fmaxf(acc[mt][nt][r] + bn[nt], 0.f) * rs;
                            C[(size_t)row * N + n0 + wn + nt * 16 + mrow] = f2b(v);
                        }
                    }
                }
            }
        } else {
            #pragma unroll
            for (int nt = 0; nt < 4; ++nt) {
                float v0 = 0.f, v1 = 0.f;
                #pragma unroll
                for (int mt = 0; mt < 2; ++mt)
                    #pragma unroll
                    for (int r = 0; r < 4; ++r) {
                        if (rok[mt * 4 + r]) {
                            float v = fmaxf(acc[mt][nt][r] + bn[nt], 0.f);
                            if (gid[mt * 4 + r] == g0) v0 = fmaxf(v0, v);
                            else v1 = fmaxf(v1, v);
                        }
                    }
                v0 = fmaxf(v0, __shfl_xor(v0, 16, 64));
                v0 = fmaxf(v0, __shfl_xor(v0, 32, 64));
                v1 = fmaxf(v1, __shfl_xor(v1, 16, 64));
                v1 = fmaxf(v1, __shfl_xor(v1, 32, 64));
                if (quad == 0) {
                    int c = wn + nt * 16 + mrow;
                    pools[wm >> 5][0][c] = v0;
                    pools[wm >> 5][1][c] = v1;
                }
            }
            __syncthreads();
            int c = tid & 127, gi = tid >> 7;
            float v = fmaxf(pools[0][gi][c], pools[1][gi][c]);
            int g = gi ? gl : g0;
            if (gi == 0 || gl != g0)
                atomicMax(&gp[(size_t)g * N + n0 + c], __float_as_int(v));
            __syncthreads();
        }
    }
}

// ---------- generic MFMA GEMM (FC head): CMODE 0 bf16+relu / 1 fp32 no relu; AFP fp32-A ----------
template <int CMODE, int AFP>
__global__ __launch_bounds__(256) void k_gemm_mfma(const void* __restrict__ Av,
                                                   const unsigned short* __restrict__ WT,
                                                   const float* __restrict__ bias,
                                                   void* __restrict__ Cv,
                                                   int M, int N, int K) {
    constexpr int LDK = 40;
    __shared__ unsigned short As[64 * LDK];
    __shared__ unsigned short Bs[128 * LDK];
    const int tid = threadIdx.x;
    const int m0 = blockIdx.y * 64, n0 = blockIdx.x * 128;
    const int wave = tid >> 6, lane = tid & 63;
    const int wm = (wave >> 1) * 32;
    const int wn = (wave & 1) * 64;
    const int quad = lane >> 4, mrow = lane & 15;

    const int ar = tid >> 2;
    const int ak = (tid & 3) * 8;
    const bool arow_ok = (m0 + ar) < M;
    const size_t aoff = (size_t)(m0 + ar) * K + ak;
    const unsigned short* Bg0 = WT + (size_t)(n0 + ar) * K + ak;
    const unsigned short* Bg1 = WT + (size_t)(n0 + ar + 64) * K + ak;

    f32x4 acc[2][4] = {};

    for (int k0 = 0; k0 < K; k0 += 32) {
        u16x8 av = {};
        if (arow_ok) {
            if constexpr (AFP) {
                const float* Af = (const float*)Av + aoff + k0;
                float4 f0 = *(const float4*)Af;
                float4 f1 = *(const float4*)(Af + 4);
                av[0] = (short)f2b(f0.x); av[1] = (short)f2b(f0.y);
                av[2] = (short)f2b(f0.z); av[3] = (short)f2b(f0.w);
                av[4] = (short)f2b(f1.x); av[5] = (short)f2b(f1.y);
                av[6] = (short)f2b(f1.z); av[7] = (short)f2b(f1.w);
            } else {
                av = *(const u16x8*)((const unsigned short*)Av + aoff + k0);
            }
        }
        u16x8 bv0 = *(const u16x8*)(Bg0 + k0);
        u16x8 bv1 = *(const u16x8*)(Bg1 + k0);
        *(u16x8*)&As[ar * LDK + ak] = av;
        *(u16x8*)&Bs[ar * LDK + ak] = bv0;
        *(u16x8*)&Bs[(ar + 64) * LDK + ak] = bv1;
        __syncthreads();
        bf16x8 af[2], bf[4];
        #pragma unroll
        for (int mt = 0; mt < 2; ++mt)
            af[mt] = *(const bf16x8*)&As[(wm + mt * 16 + mrow) * LDK + quad * 8];
        #pragma unroll
        for (int nt = 0; nt < 4; ++nt)
            bf[nt] = *(const bf16x8*)&Bs[(wn + nt * 16 + mrow) * LDK + quad * 8];
        #pragma unroll
        for (int mt = 0; mt < 2; ++mt)
            #pragma unroll
            for (int nt = 0; nt < 4; ++nt)
                acc[mt][nt] = __builtin_amdgcn_mfma_f32_16x16x32_bf16(af[mt], bf[nt], acc[mt][nt], 0, 0, 0);
        __syncthreads();
    }

    float bn[4];
    #pragma unroll
    for (int nt = 0; nt < 4; ++nt) bn[nt] = bias[n0 + wn + nt * 16 + mrow];

    if constexpr (CMODE == 0) {
        unsigned short* C = (unsigned short*)Cv;
        #pragma unroll
        for (int mt = 0; mt < 2; ++mt) {
            #pragma unroll
            for (int r = 0; r < 4; ++r) {
                int row = m0 + wm + mt * 16 + quad * 4 + r;
                if (row < M) {
                    #pragma unroll
                    for (int nt = 0; nt < 4; ++nt) {
                        float v = fmaxf(acc[mt][nt][r] + bn[nt], 0.f);
                        C[(size_t)row * N + n0 + wn + nt * 16 + mrow] = f2b(v);
                    }
                }
            }
        }
    } else {
        float* C = (float*)Cv;
        #pragma unroll
        for (int mt = 0; mt < 2; ++mt) {
            #pragma unroll
            for (int r = 0; r < 4; ++r) {
                int row = m0 + wm + mt * 16 + quad * 4 + r;
                if (row < M) {
                    #pragma unroll
                    for (int nt = 0; nt < 4; ++nt)
                        C[(size_t)row * N + n0 + wn + nt * 16 + mrow] = acc[mt][nt][r] + bn[nt];
                }
            }
        }
    }
}

extern "C" void kernel_launch(void* const* d_in, const int* in_sizes, int n_in,
                              void* d_out, int out_size, void* d_ws, size_t ws_size,
                              hipStream_t stream) {
    const float* x   = (const float*)d_in[0];
    const float* ew  = (const float*)d_in[1];
    const float* W1  = (const float*)d_in[2];
    const float* b1  = (const float*)d_in[3];
    const float* W2  = (const float*)d_in[4];
    const float* b2  = (const float*)d_in[5];
    const float* W3  = (const float*)d_in[6];
    const float* b3  = (const float*)d_in[7];
    const float* Wf1 = (const float*)d_in[8];
    const float* bf1 = (const float*)d_in[9];
    const float* Wf2 = (const float*)d_in[10];
    const float* bf2 = (const float*)d_in[11];
    const int* ei    = (const int*)d_in[12];
    const int* batch = (const int*)d_in[13];
    float* out = (float*)d_out;
    (void)in_sizes; (void)n_in; (void)out_size; (void)ws_size;

    char* p = (char*)d_ws;
    auto alloc = [&](size_t bytes) -> char* {
        char* r = p;
        p += (bytes + 255) & ~(size_t)255;
        return r;
    };
    const int nbN = (NNODES + 255) / 256;   // 196
    u64*   deg_cnt = (u64*)alloc((size_t)NNODES * 8);
    float* dinv   = (float*)alloc((size_t)NNODES * 4);
    unsigned* edges = (unsigned*)alloc((size_t)NNODES * DCAP * 4);  // padded CSR, 9.6 MB
    int*   gp     = (int*)  alloc((size_t)NGRAPH * 512 * 4);
    unsigned short* f1   = (unsigned short*)alloc((size_t)NGRAPH * 1024 * 2);
    unsigned short* wt1  = (unsigned short*)alloc((size_t)128 * 128 * 2);
    unsigned short* wt2  = (unsigned short*)alloc((size_t)256 * 128 * 2);
    unsigned short* wt3  = (unsigned short*)alloc((size_t)512 * 256 * 2);
    unsigned short* wtf1 = (unsigned short*)alloc((size_t)1024 * 512 * 2);
    unsigned short* wtf2 = (unsigned short*)alloc((size_t)128 * 1024 * 2);
    unsigned short* bufA = (unsigned short*)alloc((size_t)NNODES * 256 * 2);
    unsigned short* bufB = (unsigned short*)alloc((size_t)NNODES * 256 * 2);
    unsigned short* x16  = bufB;   // consumed by agg-1 before gemm-1 overwrites bufB
    // total ~65 MB

    const int MB = (NNODES + 63) / 64;      // 782
    const int AGG = (NNODES + 3) / 4;

    // graph preprocessing
    k_setup<<<1024, 256, 0, stream>>>(deg_cnt, gp);
    k_count<<<(NEDGES / 4 + 255) / 256, 256, 0, stream>>>(
        (const int4*)ei, (const int4*)(ei + NEDGES), (const float4*)ew, deg_cnt, edges);
    k_prep<<<nbN, 256, 0, stream>>>(deg_cnt, dinv);
    k_wt_all<<<(835584 + 255) / 256, 256, 0, stream>>>(W1, W2, W3, Wf1, Wf2,
                                                       wt1, wt2, wt3, wtf1, wtf2);
    k_cvt4<<<(NNODES * 32 + 255) / 256, 256, 0, stream>>>(x, dinv, x16, NNODES * 32);

    // layer 1: Z1 = dinv*(x' + A@x'); h1' = dinv*relu(Z1@W1+b1)
    k_aggregate<2><<<AGG, 256, 0, stream>>>(x16, deg_cnt, edges, dinv, bufA);
    k_gemm_conv<0, 128><<<MB, 256, 0, stream>>>(bufA, wt1, b1, bufB, batch, nullptr, dinv, NNODES, 128);
    // layer 2
    k_aggregate<2><<<AGG, 256, 0, stream>>>(bufB, deg_cnt, edges, dinv, bufA);
    k_gemm_conv<0, 128><<<MB, 256, 0, stream>>>(bufA, wt2, b2, bufB, batch, nullptr, dinv, NNODES, 256);
    // layer 3 + fused pool (unscaled relu feeds the pool)
    k_aggregate<4><<<AGG, 256, 0, stream>>>(bufB, deg_cnt, edges, dinv, bufA);
    k_gemm_conv<2, 256><<<MB, 256, 0, stream>>>(bufA, wt3, b3, nullptr, batch, gp, nullptr, NNODES, 512);

    // MLP head
    k_gemm_mfma<0, 1><<<dim3(8, NGRAPH / 64), 256, 0, stream>>>(gp, wtf1, bf1, f1, NGRAPH, 1024, 512);
    k_gemm_mfma<1, 0><<<dim3(1, NGRAPH / 64), 256, 0, stream>>>(f1, wtf2, bf2, out, NGRAPH, 128, 1024);
}

// Round 14
// 370.066 us; speedup vs baseline: 1.0469x; 1.0469x over previous
//
#include <hip/hip_runtime.h>

#define NNODES 50000
#define NEDGES 800000
#define NGRAPH 512
#define DCAP 64   // padded edge slots per node; Poisson(16) max ~37, P(>=64) ~ 1e-23

typedef short bf16x8 __attribute__((ext_vector_type(8)));
typedef unsigned short u16x8 __attribute__((ext_vector_type(8)));
typedef float f32x4 __attribute__((ext_vector_type(4)));
typedef unsigned long long u64;

// ---------- bf16 <-> fp32 helpers ----------
static __device__ __forceinline__ float b2f(unsigned short u) {
    return __uint_as_float(((unsigned)u) << 16);
}
static __device__ __forceinline__ unsigned short f2b(float f) {
    unsigned u = __float_as_uint(f);
    unsigned r = (u + 0x7fffu + ((u >> 16) & 1u)) >> 16;  // round-nearest-even
    return (unsigned short)r;
}

// row-fragment loads (bf16 rows)
static __device__ __forceinline__ void ldrow(const unsigned short* X, size_t off, float (&v)[2]) {
    unsigned u = *(const unsigned*)(X + off);
    v[0] = b2f((unsigned short)(u & 0xffff));
    v[1] = b2f((unsigned short)(u >> 16));
}
static __device__ __forceinline__ void ldrow(const unsigned short* X, size_t off, float (&v)[4]) {
    uint2 u = *(const uint2*)(X + off);
    v[0] = b2f((unsigned short)(u.x & 0xffff));
    v[1] = b2f((unsigned short)(u.x >> 16));
    v[2] = b2f((unsigned short)(u.y & 0xffff));
    v[3] = b2f((unsigned short)(u.y >> 16));
}

// ---------- setup: deg_cnt init + gp zero ----------
__global__ void k_setup(u64* deg_cnt, int* gp) {
    int i = blockIdx.x * 256 + threadIdx.x;
    if (i < NNODES) deg_cnt[i] = (u64)(1u << 24);   // self-loop w=1 (8.24 fixed)
    if (i < NGRAPH * 512) gp[i] = 0;                // +0.0f bits; relu pool >= 0
}

// count + DIRECT padded-CSR placement (no scan, no fill pass):
// u64 atomic returns old count = this edge's slot; edges[d*DCAP + slot] = (bf16 ew, src16).
// 4 edges/thread via int4/float4 staging -> 4 independent atomic->store chains.
__global__ __launch_bounds__(256) void k_count(const int4* __restrict__ ei_s,
                                               const int4* __restrict__ ei_d,
                                               const float4* __restrict__ ew4,
                                               u64* deg_cnt,
                                               unsigned* __restrict__ edges) {
    int t = blockIdx.x * 256 + threadIdx.x;
    if (t >= NEDGES / 4) return;
    int4 ss = ei_s[t];
    int4 dd = ei_d[t];
    float4 ww = ew4[t];
    int s[4] = {ss.x, ss.y, ss.z, ss.w};
    int d[4] = {dd.x, dd.y, dd.z, dd.w};
    float w[4] = {ww.x, ww.y, ww.z, ww.w};
    int slot[4];
    #pragma unroll
    for (int u = 0; u < 4; ++u) {
        unsigned fixed = __float2uint_rn(w[u] * 16777216.0f);  // 2^24; ew in [0,1)
        u64 old = atomicAdd(&deg_cnt[d[u]], ((u64)1 << 32) | fixed);
        slot[u] = (int)(old >> 32);
        if (slot[u] > DCAP - 1) slot[u] = DCAP - 1;  // never fires (safety)
    }
    #pragma unroll
    for (int u = 0; u < 4; ++u)
        edges[((unsigned)d[u] << 6) | slot[u]] = ((unsigned)f2b(w[u]) << 16) | (unsigned)s[u];
}

// dinv from packed degree
__global__ void k_prep(const u64* __restrict__ deg_cnt, float* __restrict__ dinv) {
    int i = blockIdx.x * 256 + threadIdx.x;
    if (i < NNODES)
        dinv[i] = rsqrtf((float)(unsigned)(deg_cnt[i] & 0xffffffffull) * 5.9604645e-8f);  // *2^-24
}

// ---------- all 5 weight transposes: W[K][N] fp32 -> WT[N][K] bf16 ----------
__global__ void k_wt_all(const float* __restrict__ W1, const float* __restrict__ W2,
                         const float* __restrict__ W3, const float* __restrict__ Wf1,
                         const float* __restrict__ Wf2,
                         unsigned short* __restrict__ T1, unsigned short* __restrict__ T2,
                         unsigned short* __restrict__ T3, unsigned short* __restrict__ Tf1,
                         unsigned short* __restrict__ Tf2) {
    int i = blockIdx.x * 256 + threadIdx.x;
    const float* W; unsigned short* T; int K, ns;
    if (i < 16384)        { W = W1;  T = T1;  K = 128;  ns = 7;  }
    else if (i < 49152)   { W = W2;  T = T2;  K = 128;  ns = 8;  i -= 16384; }
    else if (i < 180224)  { W = W3;  T = T3;  K = 256;  ns = 9;  i -= 49152; }
    else if (i < 704512)  { W = Wf1; T = Tf1; K = 512;  ns = 10; i -= 180224; }
    else if (i < 835584)  { W = Wf2; T = Tf2; K = 1024; ns = 7;  i -= 704512; }
    else return;
    int k = i >> ns, n = i & ((1 << ns) - 1);
    T[(size_t)n * K + k] = f2b(W[i]);
}

// fp32 -> bf16 with per-row dinv scale: x'[i,:] = dinv[i]*x[i,:]  (F=128)
__global__ void k_cvt4(const float* __restrict__ X, const float* __restrict__ dinv,
                       unsigned short* __restrict__ Y, int n4) {
    int i = blockIdx.x * 256 + threadIdx.x;
    if (i < n4) {
        float4 v = ((const float4*)X)[i];
        float d = dinv[i >> 5];   // 32 float4 per 128-wide row
        uint2 o;
        o.x = (unsigned)f2b(v.x * d) | ((unsigned)f2b(v.y * d) << 16);
        o.y = (unsigned)f2b(v.z * d) | ((unsigned)f2b(v.w * d) << 16);
        ((uint2*)Y)[i] = o;
    }
}

// ---------- aggregation: Z[d,:] = dinv[d] * (X'[d,:] + sum_e ew_e * X'[src_e,:]) ----------
// wave-per-node; padded edge rows at node*DCAP, count from deg_cnt hi32; unroll x8 + x4 + tail.
template <int VEC>
__global__ __launch_bounds__(256) void k_aggregate(const unsigned short* __restrict__ X,
                                                   const u64* __restrict__ deg_cnt,
                                                   const unsigned* __restrict__ edges,
                                                   const float* __restrict__ dinv,
                                                   unsigned short* __restrict__ Z) {
    const int F = 64 * VEC;
    const int wave = threadIdx.x >> 6, lane = threadIdx.x & 63;
    const int node = blockIdx.x * 4 + wave;
    if (node >= NNODES) return;
    const int fo = lane * VEC;
    const float di = dinv[node];
    const int cnt = (int)(deg_cnt[node] >> 32);
    const unsigned* erow = edges + ((unsigned)node << 6);

    float acc[VEC], v[VEC];
    ldrow(X, (size_t)node * F + fo, v);
    #pragma unroll
    for (int j = 0; j < VEC; ++j) acc[j] = v[j];

    int e = 0;
    for (; e + 8 <= cnt; e += 8) {
        unsigned pk[8];
        float vv[8][VEC];
        #pragma unroll
        for (int u = 0; u < 8; ++u) pk[u] = erow[e + u];
        #pragma unroll
        for (int u = 0; u < 8; ++u) ldrow(X, (size_t)(pk[u] & 0xffffu) * F + fo, vv[u]);
        #pragma unroll
        for (int u = 0; u < 8; ++u) {
            float c = b2f((unsigned short)(pk[u] >> 16));
            #pragma unroll
            for (int j = 0; j < VEC; ++j) acc[j] += c * vv[u][j];
        }
    }
    for (; e + 4 <= cnt; e += 4) {
        unsigned pk[4];
        float vv[4][VEC];
        #pragma unroll
        for (int u = 0; u < 4; ++u) pk[u] = erow[e + u];
        #pragma unroll
        for (int u = 0; u < 4; ++u) ldrow(X, (size_t)(pk[u] & 0xffffu) * F + fo, vv[u]);
        #pragma unroll
        for (int u = 0; u < 4; ++u) {
            float c = b2f((unsigned short)(pk[u] >> 16));
            #pragma unroll
            for (int j = 0; j < VEC; ++j) acc[j] += c * vv[u][j];
        }
    }
    for (; e < cnt; ++e) {
        unsigned pe = erow[e];
        float c = b2f((unsigned short)(pe >> 16));
        ldrow(X, (size_t)(pe & 0xffffu) * F + fo, v);
        #pragma unroll
        for (int j = 0; j < VEC; ++j) acc[j] += c * v[j];
    }

    if constexpr (VEC == 2) {
        unsigned o = (unsigned)f2b(di * acc[0]) | ((unsigned)f2b(di * acc[1]) << 16);
        *(unsigned*)(Z + (size_t)node * F + fo) = o;
    } else {
        uint2 o;
        o.x = (unsigned)f2b(di * acc[0]) | ((unsigned)f2b(di * acc[1]) << 16);
        o.y = (unsigned)f2b(di * acc[2]) | ((unsigned)f2b(di * acc[3]) << 16);
        *(uint2*)(Z + (size_t)node * F + fo) = o;
    }
}

// ---------- bf16 MFMA GEMM: C = epi(A[MxK] @ WT[NxK]^T + bias) ----------
// block 64(M) x 128(N), 4 waves (2x2 of 32x64), BK=32, 16x16x32 MFMA.
// CMODE 0: bf16 store + relu (optional row-scale rscale). 1: fp32 store, no relu.
// 2: fused per-graph relu+max-pool into gp. AFP: A is fp32 (converted during staging).
template <int CMODE, int AFP>
__global__ __launch_bounds__(256) void k_gemm_mfma(const void* __restrict__ Av,
                                                   const unsigned short* __restrict__ WT,
                                                   const float* __restrict__ bias,
                                                   void* __restrict__ Cv,
                                                   const int* __restrict__ batch,
                                                   int* __restrict__ gp,
                                                   const float* __restrict__ rscale,
                                                   int M, int N, int K) {
    constexpr int LDK = 40;
    __shared__ unsigned short As[64 * LDK];
    __shared__ unsigned short Bs[128 * LDK];
    const int tid = threadIdx.x;
    const int m0 = blockIdx.y * 64, n0 = blockIdx.x * 128;
    const int wave = tid >> 6, lane = tid & 63;
    const int wm = (wave >> 1) * 32;
    const int wn = (wave & 1) * 64;
    const int quad = lane >> 4, mrow = lane & 15;

    const int ar = tid >> 2;
    const int ak = (tid & 3) * 8;
    const bool arow_ok = (m0 + ar) < M;
    const size_t aoff = (size_t)(m0 + ar) * K + ak;
    const unsigned short* Bg0 = WT + (size_t)(n0 + ar) * K + ak;
    const unsigned short* Bg1 = WT + (size_t)(n0 + ar + 64) * K + ak;

    f32x4 acc[2][4] = {};

    for (int k0 = 0; k0 < K; k0 += 32) {
        u16x8 av = {};
        if (arow_ok) {
            if constexpr (AFP) {
                const float* Af = (const float*)Av + aoff + k0;
                float4 f0 = *(const float4*)Af;
                float4 f1 = *(const float4*)(Af + 4);
                av[0] = (short)f2b(f0.x); av[1] = (short)f2b(f0.y);
                av[2] = (short)f2b(f0.z); av[3] = (short)f2b(f0.w);
                av[4] = (short)f2b(f1.x); av[5] = (short)f2b(f1.y);
                av[6] = (short)f2b(f1.z); av[7] = (short)f2b(f1.w);
            } else {
                av = *(const u16x8*)((const unsigned short*)Av + aoff + k0);
            }
        }
        u16x8 bv0 = *(const u16x8*)(Bg0 + k0);
        u16x8 bv1 = *(const u16x8*)(Bg1 + k0);
        *(u16x8*)&As[ar * LDK + ak] = av;
        *(u16x8*)&Bs[ar * LDK + ak] = bv0;
        *(u16x8*)&Bs[(ar + 64) * LDK + ak] = bv1;
        __syncthreads();
        bf16x8 af[2], bf[4];
        #pragma unroll
        for (int mt = 0; mt < 2; ++mt)
            af[mt] = *(const bf16x8*)&As[(wm + mt * 16 + mrow) * LDK + quad * 8];
        #pragma unroll
        for (int nt = 0; nt < 4; ++nt)
            bf[nt] = *(const bf16x8*)&Bs[(wn + nt * 16 + mrow) * LDK + quad * 8];
        #pragma unroll
        for (int mt = 0; mt < 2; ++mt)
            #pragma unroll
            for (int nt = 0; nt < 4; ++nt)
                acc[mt][nt] = __builtin_amdgcn_mfma_f32_16x16x32_bf16(af[mt], bf[nt], acc[mt][nt], 0, 0, 0);
        __syncthreads();
    }

    float bn[4];
    #pragma unroll
    for (int nt = 0; nt < 4; ++nt) bn[nt] = bias[n0 + wn + nt * 16 + mrow];

    if constexpr (CMODE == 0) {
        unsigned short* C = (unsigned short*)Cv;
        #pragma unroll
        for (int mt = 0; mt < 2; ++mt) {
            #pragma unroll
            for (int r = 0; r < 4; ++r) {
                int row = m0 + wm + mt * 16 + quad * 4 + r;
                if (row < M) {
                    float rs = rscale ? rscale[row] : 1.0f;
                    #pragma unroll
                    for (int nt = 0; nt < 4; ++nt) {
                        float v = fmaxf(acc[mt][nt][r] + bn[nt], 0.f) * rs;
                        C[(size_t)row * N + n0 + wn + nt * 16 + mrow] = f2b(v);
                    }
                }
            }
        }
    } else if constexpr (CMODE == 1) {
        float* C = (float*)Cv;
        #pragma unroll
        for (int mt = 0; mt < 2; ++mt) {
            #pragma unroll
            for (int r = 0; r < 4; ++r) {
                int row = m0 + wm + mt * 16 + quad * 4 + r;
                if (row < M) {
                    #pragma unroll
                    for (int nt = 0; nt < 4; ++nt)
                        C[(size_t)row * N + n0 + wn + nt * 16 + mrow] = acc[mt][nt][r] + bn[nt];
                }
            }
        }
    } else {
        // fused pool: block's 64 rows span <=2 graphs (min graph size 97)
        __shared__ float pools[2][2][128];
        const int g0 = batch[m0];
        int last = m0 + 63; if (last >= M) last = M - 1;
        const int gl = batch[last];
        int  gid[8];
        bool rok[8];
        #pragma unroll
        for (int mt = 0; mt < 2; ++mt)
            #pragma unroll
            for (int r = 0; r < 4; ++r) {
                int row = m0 + wm + mt * 16 + quad * 4 + r;
                rok[mt * 4 + r] = row < M;
                gid[mt * 4 + r] = (row < M) ? batch[row] : -1;
            }
        #pragma unroll
        for (int nt = 0; nt < 4; ++nt) {
            float v0 = 0.f, v1 = 0.f;
            #pragma unroll
            for (int mt = 0; mt < 2; ++mt)
                #pragma unroll
                for (int r = 0; r < 4; ++r) {
                    if (rok[mt * 4 + r]) {
                        float v = fmaxf(acc[mt][nt][r] + bn[nt], 0.f);
                        if (gid[mt * 4 + r] == g0) v0 = fmaxf(v0, v);
                        else v1 = fmaxf(v1, v);
                    }
                }
            v0 = fmaxf(v0, __shfl_xor(v0, 16, 64));
            v0 = fmaxf(v0, __shfl_xor(v0, 32, 64));
            v1 = fmaxf(v1, __shfl_xor(v1, 16, 64));
            v1 = fmaxf(v1, __shfl_xor(v1, 32, 64));
            if (quad == 0) {
                int c = wn + nt * 16 + mrow;
                pools[wm >> 5][0][c] = v0;
                pools[wm >> 5][1][c] = v1;
            }
        }
        __syncthreads();
        int c = tid & 127, gi = tid >> 7;
        float v = fmaxf(pools[0][gi][c], pools[1][gi][c]);
        int g = gi ? gl : g0;
        if (gi == 0 || gl != g0)
            atomicMax(&gp[(size_t)g * N + n0 + c], __float_as_int(v));
    }
}

extern "C" void kernel_launch(void* const* d_in, const int* in_sizes, int n_in,
                              void* d_out, int out_size, void* d_ws, size_t ws_size,
                              hipStream_t stream) {
    const float* x   = (const float*)d_in[0];
    const float* ew  = (const float*)d_in[1];
    const float* W1  = (const float*)d_in[2];
    const float* b1  = (const float*)d_in[3];
    const float* W2  = (const float*)d_in[4];
    const float* b2  = (const float*)d_in[5];
    const float* W3  = (const float*)d_in[6];
    const float* b3  = (const float*)d_in[7];
    const float* Wf1 = (const float*)d_in[8];
    const float* bf1 = (const float*)d_in[9];
    const float* Wf2 = (const float*)d_in[10];
    const float* bf2 = (const float*)d_in[11];
    const int* ei    = (const int*)d_in[12];
    const int* batch = (const int*)d_in[13];
    float* out = (float*)d_out;
    (void)in_sizes; (void)n_in; (void)out_size; (void)ws_size;

    char* p = (char*)d_ws;
    auto alloc = [&](size_t bytes) -> char* {
        char* r = p;
        p += (bytes + 255) & ~(size_t)255;
        return r;
    };
    const int nbN = (NNODES + 255) / 256;   // 196
    u64*   deg_cnt = (u64*)alloc((size_t)NNODES * 8);
    float* dinv   = (float*)alloc((size_t)NNODES * 4);
    unsigned* edges = (unsigned*)alloc((size_t)NNODES * DCAP * 4);  // padded CSR, 12.8 MB
    int*   gp     = (int*)  alloc((size_t)NGRAPH * 512 * 4);
    unsigned short* f1   = (unsigned short*)alloc((size_t)NGRAPH * 1024 * 2);
    unsigned short* wt1  = (unsigned short*)alloc((size_t)128 * 128 * 2);
    unsigned short* wt2  = (unsigned short*)alloc((size_t)256 * 128 * 2);
    unsigned short* wt3  = (unsigned short*)alloc((size_t)512 * 256 * 2);
    unsigned short* wtf1 = (unsigned short*)alloc((size_t)1024 * 512 * 2);
    unsigned short* wtf2 = (unsigned short*)alloc((size_t)128 * 1024 * 2);
    unsigned short* bufA = (unsigned short*)alloc((size_t)NNODES * 256 * 2);
    unsigned short* bufB = (unsigned short*)alloc((size_t)NNODES * 256 * 2);
    unsigned short* x16  = bufB;   // consumed by agg-1 before gemm-1 overwrites bufB
    // total ~68 MB

    const int MB = (NNODES + 63) / 64;      // 782
    const int AGG = (NNODES + 3) / 4;

    // graph preprocessing: 3 kernels total
    k_setup<<<1024, 256, 0, stream>>>(deg_cnt, gp);
    k_count<<<(NEDGES / 4 + 255) / 256, 256, 0, stream>>>(
        (const int4*)ei, (const int4*)(ei + NEDGES), (const float4*)ew, deg_cnt, edges);
    k_prep<<<nbN, 256, 0, stream>>>(deg_cnt, dinv);
    k_wt_all<<<(835584 + 255) / 256, 256, 0, stream>>>(W1, W2, W3, Wf1, Wf2,
                                                       wt1, wt2, wt3, wtf1, wtf2);
    k_cvt4<<<(NNODES * 32 + 255) / 256, 256, 0, stream>>>(x, dinv, x16, NNODES * 32);

    // layer 1: Z1 = dinv*(x' + A@x'); h1' = dinv*relu(Z1@W1+b1)
    k_aggregate<2><<<AGG, 256, 0, stream>>>(x16, deg_cnt, edges, dinv, bufA);
    k_gemm_mfma<0, 0><<<dim3(1, MB), 256, 0, stream>>>(bufA, wt1, b1, bufB, batch, nullptr, dinv, NNODES, 128, 128);
    // layer 2
    k_aggregate<2><<<AGG, 256, 0, stream>>>(bufB, deg_cnt, edges, dinv, bufA);
    k_gemm_mfma<0, 0><<<dim3(2, MB), 256, 0, stream>>>(bufA, wt2, b2, bufB, batch, nullptr, dinv, NNODES, 256, 128);
    // layer 3 + fused pool (unscaled relu feeds the pool)
    k_aggregate<4><<<AGG, 256, 0, stream>>>(bufB, deg_cnt, edges, dinv, bufA);
    k_gemm_mfma<2, 0><<<dim3(4, MB), 256, 0, stream>>>(bufA, wt3, b3, nullptr, batch, gp, nullptr, NNODES, 512, 256);

    // MLP head
    k_gemm_mfma<0, 1><<<dim3(8, NGRAPH / 64), 256, 0, stream>>>(gp, wtf1, bf1, f1, batch, nullptr, nullptr, NGRAPH, 1024, 512);
    k_gemm_mfma<1, 0><<<dim3(1, NGRAPH / 64), 256, 0, stream>>>(f1, wtf2, bf2, out, batch, nullptr, nullptr, NGRAPH, 128, 1024);
}